// Round 20
// baseline (17105.872 us; speedup 1.0000x reference)
//
#include <hip/hip_runtime.h>
#include <cstdint>
#include <cstddef>

#define T_LEN 8192
#define EMB 256
#define HD 256          // hidden per direction
#define G4 1024         // 4*HD
#define NT 16
#define START_IX 14
#define STOP_IX 15

#define SLICE 8         // h outputs per WG per direction
#define ROWS2 64        // gate rows per WG total (32 fwd + 32 bwd)
#define WPAD 260        // 1040B row stride: b128-legal + bank-balanced
#define SENT 0xFFFFFFFFu

// ---------------------------------------------------------------------------
// shared-memory union: scan state vs gemm staging (different block roles)
// ---------------------------------------------------------------------------
struct ScanS {
    float w[ROWS2 * WPAD];    // rows 0-31 fwd gate-rows, 32-63 bwd (66560 B)
    float hf[256];
    float hb[256];
    float part[ROWS2 * 9];    // partial[row][seg], 9-pad (2-way = free)
    float xwr[16][2][32];     // xw ring: [step%16][dir][row] (4 KB)
};
struct GemmS {
    float at[32][65];
    float bt[128][65];
};
#define SMEM_BYTES 83968   // > 81920 -> exactly 1 block/CU (256 blocks = 256 CUs)

// ---------------------------------------------------------------------------
// h poll (proven r2/r5/r15/r19): pure agent-scope sentinel spin.
// ---------------------------------------------------------------------------
__device__ __forceinline__ unsigned poll_h(const unsigned* __restrict__ p) {
    unsigned v; int spin = 0;
    do {
        v = __hip_atomic_load(p, __ATOMIC_RELAXED, __HIP_MEMORY_SCOPE_AGENT);
    } while (v == SENT && ++spin < (1 << 20));
    return v;
}

__device__ __forceinline__ unsigned poll_sent(const unsigned* p) {
    unsigned v; int spin = 0;
    do {
        v = __hip_atomic_load(p, __ATOMIC_RELAXED, __HIP_MEMORY_SCOPE_AGENT);
    } while (v == SENT && ++spin < (1 << 20));
    return v;
}

// ---------------------------------------------------------------------------
// Fused kernel. grid 256, block 512.
//  blockIdx%8 == 0 -> scan block, wsl = blockIdx>>3 (0..31): fwd+bwd slice
//  blockIdx%8 != 0 -> gemm filler computing xw
// r20 3-phase iteration (vs r19's 4-phase: exchange paid ONCE not twice):
//   A: mv_both(t)  [both directions' matvecs — independent work, same total
//      LDS traffic as r19's two phases, one phase]            | B1 |
//   B: produce_f(wave0) & produce_b(wave1) & xw-prefetch      | B2 |
//   C: ALL 512 lanes poll hf(t)+hb(t), 1 item/lane            | B3
// Key differences from failed r12 (21ms): polls in their OWN phase one full
// phase after the stores (first sample reads MALL ~500cy post-store -> hit),
// and exactly 1 poll per lane (r12 had 2 serial + co-phased with produce).
// Skew-lock: X.C(t) waits on Y.B(t); Y.B(t) follows Y.C(t-1) which waited
// on X.B(t-1) -> lockstep +-1 phase, no deadlock. h words written once per
// launch (sentinel transport): no parity, no ABA.
// ---------------------------------------------------------------------------
__global__ __launch_bounds__(512) void k_fused(
    const int* __restrict__ sent, const float* __restrict__ embed,
    const float* __restrict__ wih_f, const float* __restrict__ wih_b,
    const float* __restrict__ bih_f, const float* __restrict__ bhh_f,
    const float* __restrict__ bih_b, const float* __restrict__ bhh_b,
    const float* __restrict__ whh_f, const float* __restrict__ whh_b,
    const float* __restrict__ h0, const float* __restrict__ c0,
    float* __restrict__ xw, float* __restrict__ h_hist)
{
    __shared__ __align__(16) char smraw[SMEM_BYTES];
    const int tid = threadIdx.x;

    if ((blockIdx.x & 7) != 0) {
        // ================= gemm filler =================
        GemmS* G = (GemmS*)smraw;
        const int f = (blockIdx.x >> 3) * 7 + (blockIdx.x & 7) - 1;  // 0..223
        const int tx = tid & 31, ty = tid >> 5;                      // 32 x 16
        for (int u = f; u < 4096; u += 224) {
            const int t_tile = u >> 4, sub = u & 15;
            const int dir = sub >> 3, r_tile = sub & 7;
            const float* __restrict__ wih = dir ? wih_b : wih_f;
            const float* __restrict__ bih = dir ? bih_b : bih_f;
            const float* __restrict__ bhh = dir ? bhh_b : bhh_f;
            const int t0 = t_tile * 32, r0 = r_tile * 128;
            float acc[2][4] = {};
            for (int k0 = 0; k0 < EMB; k0 += 64) {
                __syncthreads();   // protect staging buffers
                for (int i = tid; i < 32 * 64; i += 512) {
                    int row = i >> 6, k = i & 63;
                    int t = t0 + row;
                    int ts = dir ? (T_LEN - 1 - t) : t;
                    G->at[row][k] = embed[(size_t)sent[ts] * EMB + k0 + k];
                }
                for (int i = tid; i < 128 * 64; i += 512) {
                    int row = i >> 6, k = i & 63;
                    G->bt[row][k] = wih[(size_t)(r0 + row) * EMB + k0 + k];
                }
                __syncthreads();
#pragma unroll 16
                for (int kc = 0; kc < 64; ++kc) {
                    float a[2], b[4];
#pragma unroll
                    for (int v = 0; v < 2; ++v) a[v] = G->at[ty * 2 + v][kc];
#pragma unroll
                    for (int v = 0; v < 4; ++v) b[v] = G->bt[tx * 4 + v][kc];
#pragma unroll
                    for (int v = 0; v < 2; ++v)
#pragma unroll
                        for (int w = 0; w < 4; ++w) acc[v][w] += a[v] * b[w];
                }
            }
#pragma unroll
            for (int v = 0; v < 2; ++v) {
                int t = t0 + ty * 2 + v;
#pragma unroll
                for (int w = 0; w < 4; ++w) {
                    int r = r0 + tx * 4 + w;
                    float val = acc[v][w] + bih[r] + bhh[r];
                    __hip_atomic_store(
                        (unsigned*)&xw[((size_t)dir * T_LEN + t) * G4 + r],
                        __float_as_uint(val),
                        __ATOMIC_RELAXED, __HIP_MEMORY_SCOPE_AGENT);
                }
            }
        }
        return;
    }

    // ================= scan block =================
    ScanS* S = (ScanS*)smraw;
    const int wsl = blockIdx.x >> 3;      // 0..31
    const int wave = tid >> 6, lane = tid & 63;

    // stage both directions' weights once: row r: dir=r>>5, lr=r&31,
    // gate g=lr>>3, j=lr&7 -> global gate-row R = g*256 + wsl*8 + j
    for (int i = tid; i < ROWS2 * 256; i += 512) {
        int r = i >> 8, k = i & 255;
        int d = r >> 5, lr = r & 31;
        int R = ((lr >> 3) << 8) + wsl * SLICE + (lr & 7);
        S->w[r * WPAD + k] = (d ? whh_b : whh_f)[(size_t)R * HD + k];
    }
    if (tid < 256) { S->hf[tid] = h0[tid]; S->hb[tid] = h0[256 + tid]; }
    float c_f = 0.f, c_b = 0.f;
    if (wave == 0 && lane < 8) c_f = c0[wsl * SLICE + lane];
    if (wave == 1 && lane < 8) c_b = c0[256 + wsl * SLICE + lane];
    // xw ring init: steps 0..7 via proven agent poll (gemm runs concurrently)
    if (tid < 512) {
        int s = tid >> 6, e = tid & 63, d = e >> 5, row = e & 31;
        int R = ((row >> 3) << 8) + wsl * SLICE + (row & 7);
        unsigned v = poll_sent(
            (const unsigned*)&xw[((size_t)d * T_LEN + s) * G4 + R]);
        S->xwr[s][d][row] = __uint_as_float(v);
    }
    __syncthreads();

    float* __restrict__ hhf = h_hist;
    float* __restrict__ hhb = h_hist + (size_t)T_LEN * HD;

    for (int t = 0; t < T_LEN; ++t) {
        // ---- A: mv_both. lane = row (0..63: 32 fwd + 32 bwd),
        //      wave = k-seg (32 k), 8 b128 weight reads + 8 b128 h
        //      broadcasts (2 distinct addrs/instr = free 2-way) ----
        {
            const float4* wr = (const float4*)&S->w[lane * WPAD + wave * 32];
            const float4* hp = (const float4*)
                ((lane < 32 ? S->hf : S->hb) + wave * 32);
            float a0 = 0.f, a1 = 0.f, a2 = 0.f, a3 = 0.f;
#pragma unroll
            for (int i = 0; i < 8; ++i) {
                float4 wv = wr[i], hv = hp[i];
                a0 += wv.x * hv.x; a1 += wv.y * hv.y;
                a2 += wv.z * hv.z; a3 += wv.w * hv.w;
            }
            S->part[lane * 9 + wave] = (a0 + a1) + (a2 + a3);
        }
        __syncthreads();   // B1

        // ---- B: produce both directions in parallel + xw prefetch ----
        if (wave == 0) {
            // produce_f: r = fwd gate-row 0..31
            const int r = lane & 31;
            float xwv = S->xwr[t & 15][0][r];
            if (__builtin_amdgcn_ballot_w64(__float_as_uint(xwv) == SENT)) {
                int R = ((r >> 3) << 8) + wsl * SLICE + (r & 7);
                xwv = __uint_as_float(poll_sent(
                    (const unsigned*)&xw[(size_t)t * G4 + R]));
            }
            float z = xwv;
#pragma unroll
            for (int s = 0; s < 8; ++s) z += S->part[r * 9 + s];
            float a = ((r >> 3) == 2) ? tanhf(z) : 1.f / (1.f + expf(-z));
            const int j = r & 7;
            float af = __shfl(a, 8 + j);
            float ag = __shfl(a, 16 + j);
            float ao = __shfl(a, 24 + j);
            if (lane < 8) {
                c_f = af * c_f + a * ag;
                float hv = ao * tanhf(c_f);
                S->hf[wsl * SLICE + j] = hv;
                __hip_atomic_store(
                    (unsigned*)&hhf[(size_t)t * HD + wsl * SLICE + j],
                    __float_as_uint(hv),
                    __ATOMIC_RELAXED, __HIP_MEMORY_SCOPE_AGENT);
            }
        } else if (wave == 1) {
            // produce_b: part rows 32..63
            const int r = lane & 31;
            float xwv = S->xwr[t & 15][1][r];
            if (__builtin_amdgcn_ballot_w64(__float_as_uint(xwv) == SENT)) {
                int R = ((r >> 3) << 8) + wsl * SLICE + (r & 7);
                xwv = __uint_as_float(poll_sent((const unsigned*)
                    &xw[((size_t)T_LEN + t) * G4 + R]));
            }
            float z = xwv;
#pragma unroll
            for (int s = 0; s < 8; ++s) z += S->part[(32 + r) * 9 + s];
            float a = ((r >> 3) == 2) ? tanhf(z) : 1.f / (1.f + expf(-z));
            const int j = r & 7;
            float af = __shfl(a, 8 + j);
            float ag = __shfl(a, 16 + j);
            float ao = __shfl(a, 24 + j);
            if (lane < 8) {
                c_b = af * c_b + a * ag;
                float hv = ao * tanhf(c_b);
                S->hb[wsl * SLICE + j] = hv;
                __hip_atomic_store(
                    (unsigned*)&hhb[(size_t)t * HD + wsl * SLICE + j],
                    __float_as_uint(hv),
                    __ATOMIC_RELAXED, __HIP_MEMORY_SCOPE_AGENT);
            }
        } else if (wave == 5 || wave == 6) {
            // bulk xw prefetch: every 8th iter, steps t+8..t+15 (plain loads,
            // drained at B2; benign-stale + sentinel-checked at consumption)
            if ((t & 7) == 0 && t + 8 < T_LEN) {
                const int base = (wave - 5) * 64 + lane;  // 0..127
#pragma unroll
                for (int u = 0; u < 4; ++u) {
                    int item = base + u * 128;            // 0..511
                    int s = item >> 6, e = item & 63;
                    int d = e >> 5, row = e & 31;
                    int step = t + 8 + s;
                    int R = ((row >> 3) << 8) + wsl * SLICE + (row & 7);
                    S->xwr[step & 15][d][row] =
                        xw[((size_t)d * T_LEN + step) * G4 + R];
                }
            }
        }
        __syncthreads();   // B2

        // ---- C: poll phase. All 512 lanes, 1 item each: hf(t) | hb(t).
        //      First sample's load reads MALL ~500cy after the phase-B
        //      store -> usually an immediate hit (r17 proved earlier
        //      sampling misses; r12 proved co-phasing stalls). ----
        if (t + 1 < T_LEN) {
            if (tid < 256) {
                if ((tid >> 3) != wsl) {
                    unsigned v = poll_h(
                        (const unsigned*)&hhf[(size_t)t * HD + tid]);
                    S->hf[tid] = __uint_as_float(v);
                }
            } else {
                const int e = tid - 256;
                if ((e >> 3) != wsl) {
                    unsigned v = poll_h(
                        (const unsigned*)&hhb[(size_t)t * HD + e]);
                    S->hb[e] = __uint_as_float(v);
                }
            }
        }
        __syncthreads();   // B3
    }
}

// ---------------------------------------------------------------------------
// Phase C: feats. 1 tag/thread, grid 512. W_out staged in LDS.
// ---------------------------------------------------------------------------
__global__ __launch_bounds__(256) void k_feats(
    const float* __restrict__ h_hist, const float* __restrict__ Wout,
    const float* __restrict__ bout, float* __restrict__ feats)
{
    __shared__ float wlds[16][512];
    const int tid = threadIdx.x;
    for (int i = tid; i < 16 * 512; i += 256) wlds[i >> 9][i & 511] = Wout[i];
    __syncthreads();
    const int idx = blockIdx.x * 256 + tid;          // 0..131071
    const int t = idx >> 4, tg = idx & 15;           // 1 tag per thread
    const float4* hf = (const float4*)(h_hist + (size_t)t * HD);
    const float4* hb = (const float4*)(h_hist + (size_t)(T_LEN + (T_LEN - 1 - t)) * HD);
    float acc = bout[tg];
    for (int k = 0; k < 64; ++k) {
        float4 a = hf[k];
        float4 b = *(const float4*)&wlds[tg][k * 4];
        acc += a.x * b.x + a.y * b.y + a.z * b.z + a.w * b.w;
    }
    for (int k = 0; k < 64; ++k) {
        float4 a = hb[k];
        float4 b = *(const float4*)&wlds[tg][256 + k * 4];
        acc += a.x * b.x + a.y * b.y + a.z * b.z + a.w * b.w;
    }
    feats[(size_t)t * NT + tg] = acc;
}

// ---------------------------------------------------------------------------
// Phase D: Viterbi (r19 proven version: quad-DPP reduce, LDS feats double
// buffer, fp32 exact reference mirror, map-composition backtrack).
// ---------------------------------------------------------------------------
template <int CTRL>
__device__ __forceinline__ float dpp_qf(float x) {
    return __int_as_float(__builtin_amdgcn_update_dpp(
        0, __float_as_int(x), CTRL, 0xF, 0xF, true));
}
template <int CTRL>
__device__ __forceinline__ int dpp_qi(int x) {
    return __builtin_amdgcn_update_dpp(0, x, CTRL, 0xF, 0xF, true);
}
#define QP_SWAP1 0xB1   // quad_perm [1,0,3,2]
#define QP_SWAP2 0x4E   // quad_perm [2,3,0,1]

__device__ __forceinline__ unsigned bsel16(uint4 g, unsigned e) {
    unsigned wd = (e < 8u) ? ((e < 4u) ? g.x : g.y) : ((e < 12u) ? g.z : g.w);
    return (wd >> ((e & 3u) * 8u)) & 15u;
}

__global__ __launch_bounds__(256) void k_viterbi(
    const float* __restrict__ feats, const float* __restrict__ trans,
    int* __restrict__ out, unsigned char* __restrict__ bp)
{
    __shared__ int sid;
    __shared__ unsigned slo[512], shi[512];
    __shared__ float fbuf[2][256][16];    // 32 KB feats double buffer
    const int tid = threadIdx.x;
    const int wave = tid >> 6, lane = tid & 63;
    const int i = lane >> 2, jq = lane & 3;   // state, j-group (quad layout)

    for (int idx = tid; idx < 4096; idx += 256)
        fbuf[0][idx >> 4][idx & 15] = feats[idx];

    float tr[4];
    if (wave == 0) {
#pragma unroll
        for (int u = 0; u < 4; ++u) tr[u] = trans[i * 16 + jq * 4 + u];
    }
    float fvn = (i == START_IX) ? 0.0f : -10000.0f;   // quad-replicated
    __syncthreads();

    for (int chunk = 0; chunk < T_LEN / 256; ++chunk) {
        const int b = chunk & 1;
        const int base = chunk * 256;
        if (wave == 0) {
            float fA = fbuf[b][0][i];
            float fB = fbuf[b][1][i];
            for (int s = 0; s < 256; ++s) {
                float fC = (s + 2 < 256) ? fbuf[b][s + 2][i] : 0.f;

                float best = -3.4e38f; int bj = 0;
#pragma unroll
                for (int u = 0; u < 4; ++u) {
                    float fvj = __shfl(fvn, (jq * 4 + u) * 4);
                    float v = (fvj + fA) + tr[u];
                    if (v > best) { best = v; bj = jq * 4 + u; }  // first-max
                }
                {
                    float ob = dpp_qf<QP_SWAP1>(best);
                    int   oj = dpp_qi<QP_SWAP1>(bj);
                    if (ob > best || (ob == best && oj < bj)) { best = ob; bj = oj; }
                    ob = dpp_qf<QP_SWAP2>(best);
                    oj = dpp_qi<QP_SWAP2>(bj);
                    if (ob > best || (ob == best && oj < bj)) { best = ob; bj = oj; }
                }
                if (jq == 0) bp[(size_t)(base + s) * 16 + i] = (unsigned char)bj;
                fvn = best;                 // ref: fv = temp.max(axis=1)
                fA = fB; fB = fC;
            }
        } else if (chunk + 1 < T_LEN / 256) {
            const int nb = b ^ 1;
            const size_t noff = (size_t)(base + 256) * 16;
            for (int idx = (wave - 1) * 64 + lane; idx < 4096; idx += 192)
                fbuf[nb][idx >> 4][idx & 15] = feats[noff + idx];
        }
        __syncthreads();
    }

    if (wave == 0) {
        float fvi = __shfl(fvn, (lane & 15) * 4);      // fv[state=lane&15]
        float term = (lane < 16) ? fvi + trans[lane * 16 + STOP_IX] : -3.4e38f;
        int ti = lane;
#pragma unroll
        for (int off = 1; off < 16; off <<= 1) {
            float ov = __shfl_xor(term, off); int oi = __shfl_xor(ti, off);
            if (ov > term || (ov == term && oi < ti)) { term = ov; ti = oi; }
        }
        if (lane == 0) sid = ti;
    }
    __syncthreads();

    // backtrack: map-composition suffix scan (proven)
    const int j = tid;
    unsigned Flo = 0x76543210u, Fhi = 0xfedcba98u;
    for (int t = 32 * j + 31; t >= 32 * j; --t) {
        uint4 g = *(const uint4*)&bp[(size_t)t * 16];
        unsigned nlo = 0, nhi = 0;
#pragma unroll
        for (int x = 0; x < 8; ++x) {
            unsigned e = (Flo >> (x * 4)) & 15u;
            nlo |= bsel16(g, e) << (x * 4);
        }
#pragma unroll
        for (int x = 0; x < 8; ++x) {
            unsigned e = (Fhi >> (x * 4)) & 15u;
            nhi |= bsel16(g, e) << (x * 4);
        }
        Flo = nlo; Fhi = nhi;
    }
    slo[j] = Flo; shi[j] = Fhi;
    slo[j + 256] = 0x76543210u; shi[j + 256] = 0xfedcba98u;
    __syncthreads();
    for (int off = 1; off < 256; off <<= 1) {
        unsigned alo = slo[j], ahi = shi[j];
        unsigned blo = slo[j + off], bhi = shi[j + off];
        __syncthreads();
        unsigned nlo = 0, nhi = 0;
#pragma unroll
        for (int x = 0; x < 8; ++x) {
            unsigned e = (blo >> (x * 4)) & 15u;
            unsigned rr = ((e < 8u ? alo : ahi) >> ((e & 7u) * 4u)) & 15u;
            nlo |= rr << (x * 4);
        }
#pragma unroll
        for (int x = 0; x < 8; ++x) {
            unsigned e = (bhi >> (x * 4)) & 15u;
            unsigned rr = ((e < 8u ? alo : ahi) >> ((e & 7u) * 4u)) & 15u;
            nhi |= rr << (x * 4);
        }
        slo[j] = nlo; shi[j] = nhi;
        __syncthreads();
    }
    int idl = sid;
    unsigned plo = slo[j + 1], phi = shi[j + 1];
    unsigned x = (((unsigned)idl < 8u ? plo : phi) >> (((unsigned)idl & 7u) * 4u)) & 15u;
    out[32 * j + 31] = (int)x;
    for (int t = 32 * j + 30; t >= 32 * j; --t) {
        x = (unsigned)bp[(size_t)(t + 1) * 16 + x];
        out[t] = (int)x;
    }
}

// ---------------------------------------------------------------------------
extern "C" void kernel_launch(void* const* d_in, const int* in_sizes, int n_in,
                              void* d_out, int out_size, void* d_ws, size_t ws_size,
                              hipStream_t stream) {
    const int*   sent  = (const int*)  d_in[0];
    const float* embed = (const float*)d_in[1];
    const float* wih_f = (const float*)d_in[2];
    const float* whh_f = (const float*)d_in[3];
    const float* bih_f = (const float*)d_in[4];
    const float* bhh_f = (const float*)d_in[5];
    const float* wih_b = (const float*)d_in[6];
    const float* whh_b = (const float*)d_in[7];
    const float* bih_b = (const float*)d_in[8];
    const float* bhh_b = (const float*)d_in[9];
    const float* Wout  = (const float*)d_in[10];
    const float* bout  = (const float*)d_in[11];
    const float* trans = (const float*)d_in[12];
    const float* h0    = (const float*)d_in[13];
    const float* c0    = (const float*)d_in[14];
    int* out = (int*)d_out;

    float* ws_xw   = (float*)d_ws;                                  // 2*T*1024 f
    float* ws_h    = ws_xw + (size_t)2 * T_LEN * G4;                // 2*T*256 f
    float* ws_feat = ws_h + (size_t)2 * T_LEN * HD;                 // T*16 f
    unsigned char* ws_bp = (unsigned char*)(ws_feat + (size_t)T_LEN * NT); // T*16 B

    // per-launch poison (replay-safe): xw + h_hist sentinel words
    hipMemsetAsync(ws_xw, 0xFF, (size_t)2 * T_LEN * G4 * sizeof(float), stream);
    hipMemsetAsync(ws_h, 0xFF, (size_t)2 * T_LEN * HD * sizeof(float), stream);

    k_fused<<<256, 512, 0, stream>>>(sent, embed, wih_f, wih_b,
                                     bih_f, bhh_f, bih_b, bhh_b,
                                     whh_f, whh_b, h0, c0,
                                     ws_xw, ws_h);
    k_feats<<<512, 256, 0, stream>>>(ws_h, Wout, bout, ws_feat);
    k_viterbi<<<1, 256, 0, stream>>>(ws_feat, trans, out, ws_bp);
}

// Round 21
// 12844.067 us; speedup vs baseline: 1.3318x; 1.3318x over previous
//
#include <hip/hip_runtime.h>
#include <cstdint>
#include <cstddef>

#define T_LEN 8192
#define EMB 256
#define HD 256          // hidden per direction
#define G4 1024         // 4*HD
#define NT 16
#define START_IX 14
#define STOP_IX 15

#define SLICE 8         // h outputs per WG per direction
#define ROWSD 32        // gate rows per WG per direction (4 gates x 8)
#define WPAD 260        // 1040B row stride: b128-legal + bank-balanced
#define SENT 0xFFFFFFFFu

// ---------------------------------------------------------------------------
// shared-memory union: scan state vs gemm staging (different block roles)
// ---------------------------------------------------------------------------
struct ScanS {
    float wf[ROWSD * WPAD];   // fwd weights (33280 B)
    float wb[ROWSD * WPAD];   // bwd weights
    float hf[256];
    float hb[256];
    float part[ROWSD * 17];   // partial[r][q], 17-pad -> conflict-free columns
    float xwr[16][2][32];     // xw ring: [step%16][dir][row] (4 KB)
};
struct GemmS {
    float at[32][65];
    float bt[128][65];
};
#define SMEM_BYTES 83968   // > 81920 -> exactly 1 block/CU (256 blocks = 256 CUs)

// ---------------------------------------------------------------------------
// h poll (proven r2/r5/r15/r19): pure agent-scope sentinel spin. In-phase
// first sample lands ~850cy after the producer's store (2 phases distance)
// and usually hits immediately. r12/r17/r20 bracketed: ANY earlier sampling
// point exposes the ~1500-2000cy store-to-visible latency instead.
// ---------------------------------------------------------------------------
__device__ __forceinline__ unsigned poll_h(const unsigned* __restrict__ p) {
    unsigned v; int spin = 0;
    do {
        v = __hip_atomic_load(p, __ATOMIC_RELAXED, __HIP_MEMORY_SCOPE_AGENT);
    } while (v == SENT && ++spin < (1 << 20));
    return v;
}

__device__ __forceinline__ unsigned poll_sent(const unsigned* p) {
    unsigned v; int spin = 0;
    do {
        v = __hip_atomic_load(p, __ATOMIC_RELAXED, __HIP_MEMORY_SCOPE_AGENT);
    } while (v == SENT && ++spin < (1 << 20));
    return v;
}

// ---------------------------------------------------------------------------
// Fused kernel. grid 256, block 512.  (EXACT r15/r16/r19 version — proven
// 10.8ms; schedule space closed by r12/r17/r20 regressions.)
// ---------------------------------------------------------------------------
__global__ __launch_bounds__(512) void k_fused(
    const int* __restrict__ sent, const float* __restrict__ embed,
    const float* __restrict__ wih_f, const float* __restrict__ wih_b,
    const float* __restrict__ bih_f, const float* __restrict__ bhh_f,
    const float* __restrict__ bih_b, const float* __restrict__ bhh_b,
    const float* __restrict__ whh_f, const float* __restrict__ whh_b,
    const float* __restrict__ h0, const float* __restrict__ c0,
    float* __restrict__ xw, float* __restrict__ h_hist)
{
    __shared__ __align__(16) char smraw[SMEM_BYTES];
    const int tid = threadIdx.x;

    if ((blockIdx.x & 7) != 0) {
        // ================= gemm filler =================
        GemmS* G = (GemmS*)smraw;
        const int f = (blockIdx.x >> 3) * 7 + (blockIdx.x & 7) - 1;  // 0..223
        const int tx = tid & 31, ty = tid >> 5;                      // 32 x 16
        for (int u = f; u < 4096; u += 224) {
            const int t_tile = u >> 4, sub = u & 15;
            const int dir = sub >> 3, r_tile = sub & 7;
            const float* __restrict__ wih = dir ? wih_b : wih_f;
            const float* __restrict__ bih = dir ? bih_b : bih_f;
            const float* __restrict__ bhh = dir ? bhh_b : bhh_f;
            const int t0 = t_tile * 32, r0 = r_tile * 128;
            float acc[2][4] = {};
            for (int k0 = 0; k0 < EMB; k0 += 64) {
                __syncthreads();   // protect staging buffers
                for (int i = tid; i < 32 * 64; i += 512) {
                    int row = i >> 6, k = i & 63;
                    int t = t0 + row;
                    int ts = dir ? (T_LEN - 1 - t) : t;
                    G->at[row][k] = embed[(size_t)sent[ts] * EMB + k0 + k];
                }
                for (int i = tid; i < 128 * 64; i += 512) {
                    int row = i >> 6, k = i & 63;
                    G->bt[row][k] = wih[(size_t)(r0 + row) * EMB + k0 + k];
                }
                __syncthreads();
#pragma unroll 16
                for (int kc = 0; kc < 64; ++kc) {
                    float a[2], b[4];
#pragma unroll
                    for (int v = 0; v < 2; ++v) a[v] = G->at[ty * 2 + v][kc];
#pragma unroll
                    for (int v = 0; v < 4; ++v) b[v] = G->bt[tx * 4 + v][kc];
#pragma unroll
                    for (int v = 0; v < 2; ++v)
#pragma unroll
                        for (int w = 0; w < 4; ++w) acc[v][w] += a[v] * b[w];
                }
            }
#pragma unroll
            for (int v = 0; v < 2; ++v) {
                int t = t0 + ty * 2 + v;
#pragma unroll
                for (int w = 0; w < 4; ++w) {
                    int r = r0 + tx * 4 + w;
                    float val = acc[v][w] + bih[r] + bhh[r];
                    __hip_atomic_store(
                        (unsigned*)&xw[((size_t)dir * T_LEN + t) * G4 + r],
                        __float_as_uint(val),
                        __ATOMIC_RELAXED, __HIP_MEMORY_SCOPE_AGENT);
                }
            }
        }
        return;
    }

    // ================= scan block =================
    ScanS* S = (ScanS*)smraw;
    const int wsl = blockIdx.x >> 3;      // 0..31
    const int wave = tid >> 6, lane = tid & 63;

    for (int i = tid; i < ROWSD * 256; i += 512) {
        int r = i >> 8, k = i & 255;
        int R = ((r >> 3) << 8) + wsl * SLICE + (r & 7);
        S->wf[r * WPAD + k] = whh_f[(size_t)R * HD + k];
        S->wb[r * WPAD + k] = whh_b[(size_t)R * HD + k];
    }
    if (tid < 256) { S->hf[tid] = h0[tid]; S->hb[tid] = h0[256 + tid]; }
    float c_f = 0.f, c_b = 0.f;
    if (wave == 0 && lane < 8) {
        c_f = c0[wsl * SLICE + lane];
        c_b = c0[256 + wsl * SLICE + lane];
    }
    if (tid < 512) {
        int s = tid >> 6, e = tid & 63, d = e >> 5, row = e & 31;
        int R = ((row >> 3) << 8) + wsl * SLICE + (row & 7);
        unsigned v = poll_sent(
            (const unsigned*)&xw[((size_t)d * T_LEN + s) * G4 + R]);
        S->xwr[s][d][row] = __uint_as_float(v);
    }
    __syncthreads();

    float* __restrict__ hhf = h_hist;
    float* __restrict__ hhb = h_hist + (size_t)T_LEN * HD;

    for (int t = 0; t < T_LEN; ++t) {
        // ---- A: mv_f ----
        {
            const int q = tid >> 5, rr = tid & 31;
            const float4* wr = (const float4*)&S->wf[rr * WPAD + q * 16];
            const float4* hp = (const float4*)&S->hf[q * 16];
            float a0 = 0.f, a1 = 0.f, a2 = 0.f, a3 = 0.f;
#pragma unroll
            for (int i = 0; i < 4; ++i) {
                float4 wv = wr[i], hv = hp[i];
                a0 += wv.x * hv.x; a1 += wv.y * hv.y;
                a2 += wv.z * hv.z; a3 += wv.w * hv.w;
            }
            S->part[rr * 17 + q] = (a0 + a1) + (a2 + a3);
        }
        __syncthreads();   // B1

        if (wave == 0) {
            // ---- produce_f ----
            const int r = lane & 31;
            float xwv = S->xwr[t & 15][0][r];
            if (__builtin_amdgcn_ballot_w64(__float_as_uint(xwv) == SENT)) {
                int R = ((r >> 3) << 8) + wsl * SLICE + (r & 7);
                xwv = __uint_as_float(poll_sent(
                    (const unsigned*)&xw[(size_t)t * G4 + R]));
            }
            float z = xwv;
#pragma unroll
            for (int q = 0; q < 16; ++q) z += S->part[r * 17 + q];
            float a = ((r >> 3) == 2) ? tanhf(z) : 1.f / (1.f + expf(-z));
            const int j = r & 7;
            float af = __shfl(a, 8 + j);
            float ag = __shfl(a, 16 + j);
            float ao = __shfl(a, 24 + j);
            if (lane < 8) {
                c_f = af * c_f + a * ag;
                float hv = ao * tanhf(c_f);
                S->hf[wsl * SLICE + j] = hv;
                __hip_atomic_store(
                    (unsigned*)&hhf[(size_t)t * HD + wsl * SLICE + j],
                    __float_as_uint(hv),
                    __ATOMIC_RELAXED, __HIP_MEMORY_SCOPE_AGENT);
            }
        } else if (wave <= 4) {
            if (t > 0) {
                const int idx = (wave - 1) * 64 + lane;   // 0..255
                if ((idx >> 3) != wsl) {
                    unsigned v = poll_h(
                        (const unsigned*)&hhb[(size_t)(t - 1) * HD + idx]);
                    S->hb[idx] = __uint_as_float(v);
                }
            }
        } else if (wave <= 6) {
            if ((t & 7) == 0 && t + 8 < T_LEN) {
                const int base = (wave - 5) * 64 + lane;  // 0..127
#pragma unroll
                for (int u = 0; u < 4; ++u) {
                    int item = base + u * 128;            // 0..511
                    int s = item >> 6, e = item & 63;
                    int d = e >> 5, row = e & 31;
                    int step = t + 8 + s;
                    int R = ((row >> 3) << 8) + wsl * SLICE + (row & 7);
                    S->xwr[step & 15][d][row] =
                        xw[((size_t)d * T_LEN + step) * G4 + R];
                }
            }
        }
        __syncthreads();   // B2

        // ---- C: mv_b ----
        {
            const int q = tid >> 5, rr = tid & 31;
            const float4* wr = (const float4*)&S->wb[rr * WPAD + q * 16];
            const float4* hp = (const float4*)&S->hb[q * 16];
            float a0 = 0.f, a1 = 0.f, a2 = 0.f, a3 = 0.f;
#pragma unroll
            for (int i = 0; i < 4; ++i) {
                float4 wv = wr[i], hv = hp[i];
                a0 += wv.x * hv.x; a1 += wv.y * hv.y;
                a2 += wv.z * hv.z; a3 += wv.w * hv.w;
            }
            S->part[rr * 17 + q] = (a0 + a1) + (a2 + a3);
        }
        __syncthreads();   // B3

        if (wave == 0) {
            // ---- produce_b ----
            const int r = lane & 31;
            float xwv = S->xwr[t & 15][1][r];
            if (__builtin_amdgcn_ballot_w64(__float_as_uint(xwv) == SENT)) {
                int R = ((r >> 3) << 8) + wsl * SLICE + (r & 7);
                xwv = __uint_as_float(poll_sent((const unsigned*)
                    &xw[((size_t)T_LEN + t) * G4 + R]));
            }
            float z = xwv;
#pragma unroll
            for (int q = 0; q < 16; ++q) z += S->part[r * 17 + q];
            float a = ((r >> 3) == 2) ? tanhf(z) : 1.f / (1.f + expf(-z));
            const int j = r & 7;
            float af = __shfl(a, 8 + j);
            float ag = __shfl(a, 16 + j);
            float ao = __shfl(a, 24 + j);
            if (lane < 8) {
                c_b = af * c_b + a * ag;
                float hv = ao * tanhf(c_b);
                S->hb[wsl * SLICE + j] = hv;
                __hip_atomic_store(
                    (unsigned*)&hhb[(size_t)t * HD + wsl * SLICE + j],
                    __float_as_uint(hv),
                    __ATOMIC_RELAXED, __HIP_MEMORY_SCOPE_AGENT);
            }
        } else if (wave <= 4) {
            const int idx = (wave - 1) * 64 + lane;
            if ((idx >> 3) != wsl) {
                unsigned v = poll_h(
                    (const unsigned*)&hhf[(size_t)t * HD + idx]);
                S->hf[idx] = __uint_as_float(v);
            }
        }
        __syncthreads();   // B4
    }
}

// ---------------------------------------------------------------------------
// Phase C: feats. 1 tag/thread, grid 512. W_out staged in LDS.
// ---------------------------------------------------------------------------
__global__ __launch_bounds__(256) void k_feats(
    const float* __restrict__ h_hist, const float* __restrict__ Wout,
    const float* __restrict__ bout, float* __restrict__ feats)
{
    __shared__ float wlds[16][512];
    const int tid = threadIdx.x;
    for (int i = tid; i < 16 * 512; i += 256) wlds[i >> 9][i & 511] = Wout[i];
    __syncthreads();
    const int idx = blockIdx.x * 256 + tid;          // 0..131071
    const int t = idx >> 4, tg = idx & 15;           // 1 tag per thread
    const float4* hf = (const float4*)(h_hist + (size_t)t * HD);
    const float4* hb = (const float4*)(h_hist + (size_t)(T_LEN + (T_LEN - 1 - t)) * HD);
    float acc = bout[tg];
    for (int k = 0; k < 64; ++k) {
        float4 a = hf[k];
        float4 b = *(const float4*)&wlds[tg][k * 4];
        acc += a.x * b.x + a.y * b.y + a.z * b.z + a.w * b.w;
    }
    for (int k = 0; k < 64; ++k) {
        float4 a = hb[k];
        float4 b = *(const float4*)&wlds[tg][256 + k * 4];
        acc += a.x * b.x + a.y * b.y + a.z * b.z + a.w * b.w;
    }
    feats[(size_t)t * NT + tg] = acc;
}

// ---------------------------------------------------------------------------
// Phase D: Viterbi (r19 proven: quad-DPP reduce, LDS feats double buffer,
// fp32 exact reference mirror, map-composition backtrack).
// ---------------------------------------------------------------------------
template <int CTRL>
__device__ __forceinline__ float dpp_qf(float x) {
    return __int_as_float(__builtin_amdgcn_update_dpp(
        0, __float_as_int(x), CTRL, 0xF, 0xF, true));
}
template <int CTRL>
__device__ __forceinline__ int dpp_qi(int x) {
    return __builtin_amdgcn_update_dpp(0, x, CTRL, 0xF, 0xF, true);
}
#define QP_SWAP1 0xB1   // quad_perm [1,0,3,2]
#define QP_SWAP2 0x4E   // quad_perm [2,3,0,1]

__device__ __forceinline__ unsigned bsel16(uint4 g, unsigned e) {
    unsigned wd = (e < 8u) ? ((e < 4u) ? g.x : g.y) : ((e < 12u) ? g.z : g.w);
    return (wd >> ((e & 3u) * 8u)) & 15u;
}

__global__ __launch_bounds__(256) void k_viterbi(
    const float* __restrict__ feats, const float* __restrict__ trans,
    int* __restrict__ out, unsigned char* __restrict__ bp)
{
    __shared__ int sid;
    __shared__ unsigned slo[512], shi[512];
    __shared__ float fbuf[2][256][16];    // 32 KB feats double buffer
    const int tid = threadIdx.x;
    const int wave = tid >> 6, lane = tid & 63;
    const int i = lane >> 2, jq = lane & 3;   // state, j-group (quad layout)

    for (int idx = tid; idx < 4096; idx += 256)
        fbuf[0][idx >> 4][idx & 15] = feats[idx];

    float tr[4];
    if (wave == 0) {
#pragma unroll
        for (int u = 0; u < 4; ++u) tr[u] = trans[i * 16 + jq * 4 + u];
    }
    float fvn = (i == START_IX) ? 0.0f : -10000.0f;   // quad-replicated
    __syncthreads();

    for (int chunk = 0; chunk < T_LEN / 256; ++chunk) {
        const int b = chunk & 1;
        const int base = chunk * 256;
        if (wave == 0) {
            float fA = fbuf[b][0][i];
            float fB = fbuf[b][1][i];
            for (int s = 0; s < 256; ++s) {
                float fC = (s + 2 < 256) ? fbuf[b][s + 2][i] : 0.f;

                float best = -3.4e38f; int bj = 0;
#pragma unroll
                for (int u = 0; u < 4; ++u) {
                    float fvj = __shfl(fvn, (jq * 4 + u) * 4);
                    float v = (fvj + fA) + tr[u];
                    if (v > best) { best = v; bj = jq * 4 + u; }  // first-max
                }
                {
                    float ob = dpp_qf<QP_SWAP1>(best);
                    int   oj = dpp_qi<QP_SWAP1>(bj);
                    if (ob > best || (ob == best && oj < bj)) { best = ob; bj = oj; }
                    ob = dpp_qf<QP_SWAP2>(best);
                    oj = dpp_qi<QP_SWAP2>(bj);
                    if (ob > best || (ob == best && oj < bj)) { best = ob; bj = oj; }
                }
                if (jq == 0) bp[(size_t)(base + s) * 16 + i] = (unsigned char)bj;
                fvn = best;                 // ref: fv = temp.max(axis=1)
                fA = fB; fB = fC;
            }
        } else if (chunk + 1 < T_LEN / 256) {
            const int nb = b ^ 1;
            const size_t noff = (size_t)(base + 256) * 16;
            for (int idx = (wave - 1) * 64 + lane; idx < 4096; idx += 192)
                fbuf[nb][idx >> 4][idx & 15] = feats[noff + idx];
        }
        __syncthreads();
    }

    if (wave == 0) {
        float fvi = __shfl(fvn, (lane & 15) * 4);      // fv[state=lane&15]
        float term = (lane < 16) ? fvi + trans[lane * 16 + STOP_IX] : -3.4e38f;
        int ti = lane;
#pragma unroll
        for (int off = 1; off < 16; off <<= 1) {
            float ov = __shfl_xor(term, off); int oi = __shfl_xor(ti, off);
            if (ov > term || (ov == term && oi < ti)) { term = ov; ti = oi; }
        }
        if (lane == 0) sid = ti;
    }
    __syncthreads();

    // backtrack: map-composition suffix scan (proven)
    const int j = tid;
    unsigned Flo = 0x76543210u, Fhi = 0xfedcba98u;
    for (int t = 32 * j + 31; t >= 32 * j; --t) {
        uint4 g = *(const uint4*)&bp[(size_t)t * 16];
        unsigned nlo = 0, nhi = 0;
#pragma unroll
        for (int x = 0; x < 8; ++x) {
            unsigned e = (Flo >> (x * 4)) & 15u;
            nlo |= bsel16(g, e) << (x * 4);
        }
#pragma unroll
        for (int x = 0; x < 8; ++x) {
            unsigned e = (Fhi >> (x * 4)) & 15u;
            nhi |= bsel16(g, e) << (x * 4);
        }
        Flo = nlo; Fhi = nhi;
    }
    slo[j] = Flo; shi[j] = Fhi;
    slo[j + 256] = 0x76543210u; shi[j + 256] = 0xfedcba98u;
    __syncthreads();
    for (int off = 1; off < 256; off <<= 1) {
        unsigned alo = slo[j], ahi = shi[j];
        unsigned blo = slo[j + off], bhi = shi[j + off];
        __syncthreads();
        unsigned nlo = 0, nhi = 0;
#pragma unroll
        for (int x = 0; x < 8; ++x) {
            unsigned e = (blo >> (x * 4)) & 15u;
            unsigned rr = ((e < 8u ? alo : ahi) >> ((e & 7u) * 4u)) & 15u;
            nlo |= rr << (x * 4);
        }
#pragma unroll
        for (int x = 0; x < 8; ++x) {
            unsigned e = (bhi >> (x * 4)) & 15u;
            unsigned rr = ((e < 8u ? alo : ahi) >> ((e & 7u) * 4u)) & 15u;
            nhi |= rr << (x * 4);
        }
        slo[j] = nlo; shi[j] = nhi;
        __syncthreads();
    }
    int idl = sid;
    unsigned plo = slo[j + 1], phi = shi[j + 1];
    unsigned x = (((unsigned)idl < 8u ? plo : phi) >> (((unsigned)idl & 7u) * 4u)) & 15u;
    out[32 * j + 31] = (int)x;
    for (int t = 32 * j + 30; t >= 32 * j; --t) {
        x = (unsigned)bp[(size_t)(t + 1) * 16 + x];
        out[t] = (int)x;
    }
}

// ---------------------------------------------------------------------------
extern "C" void kernel_launch(void* const* d_in, const int* in_sizes, int n_in,
                              void* d_out, int out_size, void* d_ws, size_t ws_size,
                              hipStream_t stream) {
    const int*   sent  = (const int*)  d_in[0];
    const float* embed = (const float*)d_in[1];
    const float* wih_f = (const float*)d_in[2];
    const float* whh_f = (const float*)d_in[3];
    const float* bih_f = (const float*)d_in[4];
    const float* bhh_f = (const float*)d_in[5];
    const float* wih_b = (const float*)d_in[6];
    const float* whh_b = (const float*)d_in[7];
    const float* bih_b = (const float*)d_in[8];
    const float* bhh_b = (const float*)d_in[9];
    const float* Wout  = (const float*)d_in[10];
    const float* bout  = (const float*)d_in[11];
    const float* trans = (const float*)d_in[12];
    const float* h0    = (const float*)d_in[13];
    const float* c0    = (const float*)d_in[14];
    int* out = (int*)d_out;

    float* ws_xw   = (float*)d_ws;                                  // 2*T*1024 f
    float* ws_h    = ws_xw + (size_t)2 * T_LEN * G4;                // 2*T*256 f
    float* ws_feat = ws_h + (size_t)2 * T_LEN * HD;                 // T*16 f
    unsigned char* ws_bp = (unsigned char*)(ws_feat + (size_t)T_LEN * NT); // T*16 B

    // per-launch poison (replay-safe): xw + h_hist sentinel words
    hipMemsetAsync(ws_xw, 0xFF, (size_t)2 * T_LEN * G4 * sizeof(float), stream);
    hipMemsetAsync(ws_h, 0xFF, (size_t)2 * T_LEN * HD * sizeof(float), stream);

    k_fused<<<256, 512, 0, stream>>>(sent, embed, wih_f, wih_b,
                                     bih_f, bhh_f, bih_b, bhh_b,
                                     whh_f, whh_b, h0, c0,
                                     ws_xw, ws_h);
    k_feats<<<512, 256, 0, stream>>>(ws_h, Wout, bout, ws_feat);
    k_viterbi<<<1, 256, 0, stream>>>(ws_feat, trans, out, ws_bp);
}